// Round 12
// baseline (28.580 us; speedup 1.0000x reference)
//
#include <hip/hip_runtime.h>
#include <math.h>

#define NB 64
#define NS 512
#define NH 768
#define NT 3
#define EMIS_N (NB * NS * NT)   // 98304
#define NEGINF (-1e30f)
#define PSTRIDE 12              // floats per block partial in ws
#define BPB 16                  // blocks per batch (512 rows / 32)
#define NBLK 1024               // emis blocks (512 threads each)

__device__ __forceinline__ float lse3(float a, float b, float c) {
    float m = fmaxf(fmaxf(a, b), c);
    return m + __logf(__expf(a - m) + __expf(b - m) + __expf(c - m));
}

// ---------------------------------------------------------------------------
// Kernel 1: emissions = relu(hidden @ W + b) fused with per-BLOCK CRF partial.
// 1024 blocks x 512 threads. W (9 KB) staged once to LDS (plain loads +
// one __syncthreads) -> the 36 per-lane W reads ride the LDS pipe
// (ds_read_b128, same-address broadcast + 2-way alias = conflict-free),
// leaving the vmem/L1 path carrying ONLY the 96 MB hidden stream, which the
// compiler pipelines naturally against the FMAs (r3 structure, unchanged).
// ---------------------------------------------------------------------------
__global__ __launch_bounds__(512) void emis_crf_kernel(
    const float* __restrict__ hidden,   // [NB*NS, NH]
    const int*   __restrict__ labels,   // [NB, NS]
    const int*   __restrict__ mask,     // [NB, NS]
    const float* __restrict__ W,        // [NH, NT]
    const float* __restrict__ bias,     // [NT]
    const float* __restrict__ trans,    // [NT, NT]
    const float* __restrict__ startv,   // [NT]
    float* __restrict__ out,            // emissions [NB*NS, NT], then nll
    float* __restrict__ ws)             // [NBLK][PSTRIDE]
{
    __shared__ float sP[8][12];
    __shared__ alignas(16) float wlds[NH * NT];   // 9216 B

    const int tid  = threadIdx.x;
    const int lane = tid & 63;
    const int wv   = tid >> 6;               // wave 0..7
    const int wid  = blockIdx.x * 8 + wv;    // 0..8191
    const int sub  = lane & 15;              // h-chunk within row
    const int rsel = lane >> 4;              // which of the wave's 4 rows
    const int row  = wid * 4 + rsel;
    const int b    = row >> 9;               // batch
    const int p    = row & (NS - 1);         // position in sequence

    if (blockIdx.x == 0 && tid == 0) out[EMIS_N] = 0.0f;   // init nll acc

    // ---- stage W to LDS: 576 float4 chunks over 512 threads ----
    {
        const float4* Wv = reinterpret_cast<const float4*>(W);
        float4* Lv = reinterpret_cast<float4*>(wlds);
        Lv[tid] = Wv[tid];                       // 0..511
        if (tid < 64) Lv[512 + tid] = Wv[512 + tid];
    }

    // ---- hoisted scattered loads (consumed in the tail) ----
    const int* lrow = labels + b * NS;
    const int* mrow = mask   + b * NS;
    int mk = 0, labc = 0, labp = 0;
    if (sub == 0) {
        mk   = mrow[p];
        labc = lrow[p];
        labp = lrow[p - (p > 0 ? 1 : 0)];
    }

    __syncthreads();                             // W visible to all waves

    // ---- GEMV: hidden float4 stream (vmem) x W (LDS) ----
    const float* hrow = hidden + (size_t)row * NH;
    float a0 = 0.f, a1 = 0.f, a2 = 0.f;
    #pragma unroll
    for (int it = 0; it < 12; ++it) {
        const int h0 = it * 64 + sub * 4;
        const float4 x  = *reinterpret_cast<const float4*>(hrow + h0);
        const float4 q0 = *reinterpret_cast<const float4*>(wlds + h0 * 3);
        const float4 q1 = *reinterpret_cast<const float4*>(wlds + h0 * 3 + 4);
        const float4 q2 = *reinterpret_cast<const float4*>(wlds + h0 * 3 + 8);
        a0 = fmaf(x.x, q0.x, a0); a1 = fmaf(x.x, q0.y, a1); a2 = fmaf(x.x, q0.z, a2);
        a0 = fmaf(x.y, q0.w, a0); a1 = fmaf(x.y, q1.x, a1); a2 = fmaf(x.y, q1.y, a2);
        a0 = fmaf(x.z, q1.z, a0); a1 = fmaf(x.z, q1.w, a1); a2 = fmaf(x.z, q2.x, a2);
        a0 = fmaf(x.w, q2.y, a0); a1 = fmaf(x.w, q2.z, a1); a2 = fmaf(x.w, q2.w, a2);
    }
    #pragma unroll
    for (int d = 8; d; d >>= 1) {
        a0 += __shfl_xor(a0, d);
        a1 += __shfl_xor(a1, d);
        a2 += __shfl_xor(a2, d);
    }

    const float e0 = fmaxf(a0 + bias[0], 0.f);
    const float e1 = fmaxf(a1 + bias[1], 0.f);
    const float e2 = fmaxf(a2 + bias[2], 0.f);

    if (sub < 3) out[row * NT + sub] = (sub == 0) ? e0 : (sub == 1) ? e1 : e2;

    // ---- numerator term ----
    float term = 0.f;
    if (sub == 0) {
        const float esel = (labc == 0) ? e0 : (labc == 1) ? e1 : e2;
        if (p == 0) {
            term = startv[labc] + esel;               // boundary term
        } else if (mk) {
            term = trans[labp * 3 + labc] + esel;     // step term
        }
    }

    // ---- compose the wave's 4 step matrices (9 active lanes) ----
    const int il = (lane < 9) ? (lane / 3) : 0;
    const int jl = (lane < 9) ? (lane % 3) : 0;
    const float tc0 = trans[jl], tc1 = trans[3 + jl], tc2 = trans[6 + jl];
    float Pv = (il == jl) ? 0.f : NEGINF;

    const int pbase = p & ~3;
    #pragma unroll
    for (int k = 0; k < 4; ++k) {
        const int src = k << 4;
        const float ee0 = __shfl(e0, src);
        const float ee1 = __shfl(e1, src);
        const float ee2 = __shfl(e2, src);
        const int   mm  = __shfl(mk, src);
        const float Pi0 = __shfl(Pv, il * 3 + 0);
        const float Pi1 = __shfl(Pv, il * 3 + 1);
        const float Pi2 = __shfl(Pv, il * 3 + 2);
        const float ej  = (jl == 0) ? ee0 : (jl == 1) ? ee1 : ee2;
        const float q   = lse3(Pi0 + tc0, Pi1 + tc1, Pi2 + tc2) + ej;
        const bool act  = ((pbase + k) >= 1) && (mm != 0);
        Pv = act ? q : Pv;
    }

    const float np = __shfl(term, 0) + __shfl(term, 16) +
                     __shfl(term, 32) + __shfl(term, 48);

    if (lane < 9)  sP[wv][lane] = Pv;
    if (lane == 0) sP[wv][9]    = np;
    __syncthreads();
    if (wv != 0) return;

    // ---- fold 8 wave partials -> 1 block partial (wave 0) ----
    float Pb = (lane < 9) ? sP[0][lane] : 0.f;
    #pragma unroll
    for (int k = 1; k < 8; ++k) {
        const float Pi0 = __shfl(Pb, il * 3 + 0);
        const float Pi1 = __shfl(Pb, il * 3 + 1);
        const float Pi2 = __shfl(Pb, il * 3 + 2);
        const float q = lse3(Pi0 + sP[k][jl],
                             Pi1 + sP[k][3 + jl],
                             Pi2 + sP[k][6 + jl]);
        Pb = (lane < 9) ? q : Pb;
    }
    float* wp = ws + blockIdx.x * PSTRIDE;
    if (lane < 9)  wp[lane] = Pb;
    if (lane == 0) wp[9] = sP[0][9] + sP[1][9] + sP[2][9] + sP[3][9] +
                           sP[4][9] + sP[5][9] + sP[6][9] + sP[7][9];
}

// ---------------------------------------------------------------------------
// Kernel 2: combiner. One 64-lane block per batch: 16 block-partials on lanes
// 0..15 (loads issued first), 4-step ordered shfl_down tree, boundary terms,
// one atomicAdd per batch.
// ---------------------------------------------------------------------------
__global__ __launch_bounds__(64) void crf_combine(
    const float* __restrict__ emis,     // [NB*NS, NT] (= d_out)
    const int*   __restrict__ labels,   // [NB, NS]
    const int*   __restrict__ mask,     // [NB, NS]
    const float* __restrict__ startv,   // [NT]
    const float* __restrict__ endv,     // [NT]
    const float* __restrict__ ws,       // block partials
    float* __restrict__ nll)            // &d_out[EMIS_N]
{
    const int b    = blockIdx.x;
    const int lane = threadIdx.x;

    // issue partial loads first (independent of everything below)
    float P[9] = {0.f, NEGINF, NEGINF, NEGINF, 0.f, NEGINF, NEGINF, NEGINF, 0.f};
    float np = 0.f;
    if (lane < BPB) {
        const float* pa = ws + ((size_t)b * BPB + lane) * PSTRIDE;
        #pragma unroll
        for (int i = 0; i < 9; ++i) P[i] = pa[i];
        np = pa[9];
    }

    const int* mrow = mask   + b * NS;
    const int* lrow = labels + b * NS;
    int lsum = 0;
    #pragma unroll
    for (int k = 0; k < 8; ++k) lsum += mrow[lane + k * 64];
    #pragma unroll
    for (int d = 32; d; d >>= 1) lsum += __shfl_xor(lsum, d);
    const int len = lsum;

    // ordered tree over 16 partials
    #pragma unroll
    for (int d = 1; d < BPB; d <<= 1) {
        float Q[9];
        #pragma unroll
        for (int i = 0; i < 9; ++i) Q[i] = __shfl_down(P[i], d);
        const bool valid = (lane + d) < BPB;
        float R[9];
        #pragma unroll
        for (int i = 0; i < 3; ++i)
            #pragma unroll
            for (int j = 0; j < 3; ++j)
                R[i * 3 + j] = lse3(P[i * 3 + 0] + Q[0 + j],
                                    P[i * 3 + 1] + Q[3 + j],
                                    P[i * 3 + 2] + Q[6 + j]);
        #pragma unroll
        for (int i = 0; i < 9; ++i) P[i] = valid ? R[i] : P[i];
    }

    #pragma unroll
    for (int d = 32; d; d >>= 1) np += __shfl_xor(np, d);

    if (lane == 0) {
        const float* erow = emis + (size_t)b * NS * NT;
        const float a0 = startv[0] + erow[0];
        const float a1 = startv[1] + erow[1];
        const float a2 = startv[2] + erow[2];
        const float f0 = lse3(a0 + P[0], a1 + P[3], a2 + P[6]);
        const float f1 = lse3(a0 + P[1], a1 + P[4], a2 + P[7]);
        const float f2 = lse3(a0 + P[2], a1 + P[5], a2 + P[8]);
        const float logZ = lse3(f0 + endv[0], f1 + endv[1], f2 + endv[2]);

        const int tl = lrow[len - 1];
        const float num = np + endv[tl];   // start + e0 term already in np
        atomicAdd(nll, logZ - num);
    }
}

extern "C" void kernel_launch(void* const* d_in, const int* in_sizes, int n_in,
                              void* d_out, int out_size, void* d_ws, size_t ws_size,
                              hipStream_t stream) {
    const float* hidden = (const float*)d_in[0];
    const int*   labels = (const int*)  d_in[1];
    const int*   maskp  = (const int*)  d_in[2];
    const float* W      = (const float*)d_in[3];
    const float* bias   = (const float*)d_in[4];
    const float* trans  = (const float*)d_in[5];
    const float* startv = (const float*)d_in[6];
    const float* endv   = (const float*)d_in[7];
    float* out = (float*)d_out;
    float* ws  = (float*)d_ws;   // needs 1024 * 12 * 4 B = 48 KB

    emis_crf_kernel<<<NBLK, 512, 0, stream>>>(hidden, labels, maskp, W, bias,
                                              trans, startv, out, ws);
    crf_combine<<<NB, 64, 0, stream>>>(out, labels, maskp, startv, endv, ws,
                                       out + EMIS_N);
}

// Round 14
// 25.701 us; speedup vs baseline: 1.1120x; 1.1120x over previous
//
#include <hip/hip_runtime.h>
#include <math.h>

#define NB 64
#define NS 512
#define NH 768
#define NT 3
#define EMIS_N (NB * NS * NT)   // 98304
#define NEGINF (-1e30f)
#define PSTRIDE 12              // floats per block partial in ws
#define BPB 16                  // blocks per batch (512 rows / 32)
#define NBLK 1024               // emis blocks (512 threads each)

typedef float floatx4 __attribute__((ext_vector_type(4)));

__device__ __forceinline__ float lse3(float a, float b, float c) {
    float m = fmaxf(fmaxf(a, b), c);
    return m + __logf(__expf(a - m) + __expf(b - m) + __expf(c - m));
}

// ---------------------------------------------------------------------------
// Kernel 1: emissions = relu(hidden @ W + b) fused with per-BLOCK CRF partial.
// r12 structure (W in LDS, natural compiler pipelining) with ONE change:
// hidden is read via __builtin_nontemporal_load (nt-flagged global loads, no
// cache allocation) through a native ext_vector_type (the HIP float4 struct
// is rejected by the builtin). Stream has zero intra-replay reuse.
// ---------------------------------------------------------------------------
__global__ __launch_bounds__(512) void emis_crf_kernel(
    const float* __restrict__ hidden,   // [NB*NS, NH]
    const int*   __restrict__ labels,   // [NB, NS]
    const int*   __restrict__ mask,     // [NB, NS]
    const float* __restrict__ W,        // [NH, NT]
    const float* __restrict__ bias,     // [NT]
    const float* __restrict__ trans,    // [NT, NT]
    const float* __restrict__ startv,   // [NT]
    float* __restrict__ out,            // emissions [NB*NS, NT], then nll
    float* __restrict__ ws)             // [NBLK][PSTRIDE]
{
    __shared__ float sP[8][12];
    __shared__ alignas(16) float wlds[NH * NT];   // 9216 B

    const int tid  = threadIdx.x;
    const int lane = tid & 63;
    const int wv   = tid >> 6;               // wave 0..7
    const int wid  = blockIdx.x * 8 + wv;    // 0..8191
    const int sub  = lane & 15;              // h-chunk within row
    const int rsel = lane >> 4;              // which of the wave's 4 rows
    const int row  = wid * 4 + rsel;
    const int b    = row >> 9;               // batch
    const int p    = row & (NS - 1);         // position in sequence

    if (blockIdx.x == 0 && tid == 0) out[EMIS_N] = 0.0f;   // init nll acc

    // ---- stage W to LDS: 576 float4 chunks over 512 threads ----
    {
        const float4* Wv = reinterpret_cast<const float4*>(W);
        float4* Lv = reinterpret_cast<float4*>(wlds);
        Lv[tid] = Wv[tid];                       // 0..511
        if (tid < 64) Lv[512 + tid] = Wv[512 + tid];
    }

    // ---- hoisted scattered loads (consumed in the tail) ----
    const int* lrow = labels + b * NS;
    const int* mrow = mask   + b * NS;
    int mk = 0, labc = 0, labp = 0;
    if (sub == 0) {
        mk   = mrow[p];
        labc = lrow[p];
        labp = lrow[p - (p > 0 ? 1 : 0)];
    }

    __syncthreads();                             // W visible to all waves

    // ---- GEMV: nontemporal hidden float4 stream (vmem) x W (LDS) ----
    const float* hrow = hidden + (size_t)row * NH;
    float a0 = 0.f, a1 = 0.f, a2 = 0.f;
    #pragma unroll
    for (int it = 0; it < 12; ++it) {
        const int h0 = it * 64 + sub * 4;
        const floatx4 x = __builtin_nontemporal_load(
                              reinterpret_cast<const floatx4*>(hrow + h0));
        const float4 q0 = *reinterpret_cast<const float4*>(wlds + h0 * 3);
        const float4 q1 = *reinterpret_cast<const float4*>(wlds + h0 * 3 + 4);
        const float4 q2 = *reinterpret_cast<const float4*>(wlds + h0 * 3 + 8);
        a0 = fmaf(x.x, q0.x, a0); a1 = fmaf(x.x, q0.y, a1); a2 = fmaf(x.x, q0.z, a2);
        a0 = fmaf(x.y, q0.w, a0); a1 = fmaf(x.y, q1.x, a1); a2 = fmaf(x.y, q1.y, a2);
        a0 = fmaf(x.z, q1.z, a0); a1 = fmaf(x.z, q1.w, a1); a2 = fmaf(x.z, q2.x, a2);
        a0 = fmaf(x.w, q2.y, a0); a1 = fmaf(x.w, q2.z, a1); a2 = fmaf(x.w, q2.w, a2);
    }
    #pragma unroll
    for (int d = 8; d; d >>= 1) {
        a0 += __shfl_xor(a0, d);
        a1 += __shfl_xor(a1, d);
        a2 += __shfl_xor(a2, d);
    }

    const float e0 = fmaxf(a0 + bias[0], 0.f);
    const float e1 = fmaxf(a1 + bias[1], 0.f);
    const float e2 = fmaxf(a2 + bias[2], 0.f);

    if (sub < 3) out[row * NT + sub] = (sub == 0) ? e0 : (sub == 1) ? e1 : e2;

    // ---- numerator term ----
    float term = 0.f;
    if (sub == 0) {
        const float esel = (labc == 0) ? e0 : (labc == 1) ? e1 : e2;
        if (p == 0) {
            term = startv[labc] + esel;               // boundary term
        } else if (mk) {
            term = trans[labp * 3 + labc] + esel;     // step term
        }
    }

    // ---- compose the wave's 4 step matrices (9 active lanes) ----
    const int il = (lane < 9) ? (lane / 3) : 0;
    const int jl = (lane < 9) ? (lane % 3) : 0;
    const float tc0 = trans[jl], tc1 = trans[3 + jl], tc2 = trans[6 + jl];
    float Pv = (il == jl) ? 0.f : NEGINF;

    const int pbase = p & ~3;
    #pragma unroll
    for (int k = 0; k < 4; ++k) {
        const int src = k << 4;
        const float ee0 = __shfl(e0, src);
        const float ee1 = __shfl(e1, src);
        const float ee2 = __shfl(e2, src);
        const int   mm  = __shfl(mk, src);
        const float Pi0 = __shfl(Pv, il * 3 + 0);
        const float Pi1 = __shfl(Pv, il * 3 + 1);
        const float Pi2 = __shfl(Pv, il * 3 + 2);
        const float ej  = (jl == 0) ? ee0 : (jl == 1) ? ee1 : ee2;
        const float q   = lse3(Pi0 + tc0, Pi1 + tc1, Pi2 + tc2) + ej;
        const bool act  = ((pbase + k) >= 1) && (mm != 0);
        Pv = act ? q : Pv;
    }

    const float np = __shfl(term, 0) + __shfl(term, 16) +
                     __shfl(term, 32) + __shfl(term, 48);

    if (lane < 9)  sP[wv][lane] = Pv;
    if (lane == 0) sP[wv][9]    = np;
    __syncthreads();
    if (wv != 0) return;

    // ---- fold 8 wave partials -> 1 block partial (wave 0) ----
    float Pb = (lane < 9) ? sP[0][lane] : 0.f;
    #pragma unroll
    for (int k = 1; k < 8; ++k) {
        const float Pi0 = __shfl(Pb, il * 3 + 0);
        const float Pi1 = __shfl(Pb, il * 3 + 1);
        const float Pi2 = __shfl(Pb, il * 3 + 2);
        const float q = lse3(Pi0 + sP[k][jl],
                             Pi1 + sP[k][3 + jl],
                             Pi2 + sP[k][6 + jl]);
        Pb = (lane < 9) ? q : Pb;
    }
    float* wp = ws + blockIdx.x * PSTRIDE;
    if (lane < 9)  wp[lane] = Pb;
    if (lane == 0) wp[9] = sP[0][9] + sP[1][9] + sP[2][9] + sP[3][9] +
                           sP[4][9] + sP[5][9] + sP[6][9] + sP[7][9];
}

// ---------------------------------------------------------------------------
// Kernel 2: combiner. One 64-lane block per batch: 16 block-partials on lanes
// 0..15 (loads issued first), 4-step ordered shfl_down tree, boundary terms,
// one atomicAdd per batch.
// ---------------------------------------------------------------------------
__global__ __launch_bounds__(64) void crf_combine(
    const float* __restrict__ emis,     // [NB*NS, NT] (= d_out)
    const int*   __restrict__ labels,   // [NB, NS]
    const int*   __restrict__ mask,     // [NB, NS]
    const float* __restrict__ startv,   // [NT]
    const float* __restrict__ endv,     // [NT]
    const float* __restrict__ ws,       // block partials
    float* __restrict__ nll)            // &d_out[EMIS_N]
{
    const int b    = blockIdx.x;
    const int lane = threadIdx.x;

    // issue partial loads first (independent of everything below)
    float P[9] = {0.f, NEGINF, NEGINF, NEGINF, 0.f, NEGINF, NEGINF, NEGINF, 0.f};
    float np = 0.f;
    if (lane < BPB) {
        const float* pa = ws + ((size_t)b * BPB + lane) * PSTRIDE;
        #pragma unroll
        for (int i = 0; i < 9; ++i) P[i] = pa[i];
        np = pa[9];
    }

    const int* mrow = mask   + b * NS;
    const int* lrow = labels + b * NS;
    int lsum = 0;
    #pragma unroll
    for (int k = 0; k < 8; ++k) lsum += mrow[lane + k * 64];
    #pragma unroll
    for (int d = 32; d; d >>= 1) lsum += __shfl_xor(lsum, d);
    const int len = lsum;

    // ordered tree over 16 partials
    #pragma unroll
    for (int d = 1; d < BPB; d <<= 1) {
        float Q[9];
        #pragma unroll
        for (int i = 0; i < 9; ++i) Q[i] = __shfl_down(P[i], d);
        const bool valid = (lane + d) < BPB;
        float R[9];
        #pragma unroll
        for (int i = 0; i < 3; ++i)
            #pragma unroll
            for (int j = 0; j < 3; ++j)
                R[i * 3 + j] = lse3(P[i * 3 + 0] + Q[0 + j],
                                    P[i * 3 + 1] + Q[3 + j],
                                    P[i * 3 + 2] + Q[6 + j]);
        #pragma unroll
        for (int i = 0; i < 9; ++i) P[i] = valid ? R[i] : P[i];
    }

    #pragma unroll
    for (int d = 32; d; d >>= 1) np += __shfl_xor(np, d);

    if (lane == 0) {
        const float* erow = emis + (size_t)b * NS * NT;
        const float a0 = startv[0] + erow[0];
        const float a1 = startv[1] + erow[1];
        const float a2 = startv[2] + erow[2];
        const float f0 = lse3(a0 + P[0], a1 + P[3], a2 + P[6]);
        const float f1 = lse3(a0 + P[1], a1 + P[4], a2 + P[7]);
        const float f2 = lse3(a0 + P[2], a1 + P[5], a2 + P[8]);
        const float logZ = lse3(f0 + endv[0], f1 + endv[1], f2 + endv[2]);

        const int tl = lrow[len - 1];
        const float num = np + endv[tl];   // start + e0 term already in np
        atomicAdd(nll, logZ - num);
    }
}

extern "C" void kernel_launch(void* const* d_in, const int* in_sizes, int n_in,
                              void* d_out, int out_size, void* d_ws, size_t ws_size,
                              hipStream_t stream) {
    const float* hidden = (const float*)d_in[0];
    const int*   labels = (const int*)  d_in[1];
    const int*   maskp  = (const int*)  d_in[2];
    const float* W      = (const float*)d_in[3];
    const float* bias   = (const float*)d_in[4];
    const float* trans  = (const float*)d_in[5];
    const float* startv = (const float*)d_in[6];
    const float* endv   = (const float*)d_in[7];
    float* out = (float*)d_out;
    float* ws  = (float*)d_ws;   // needs 1024 * 12 * 4 B = 48 KB

    emis_crf_kernel<<<NBLK, 512, 0, stream>>>(hidden, labels, maskp, W, bias,
                                              trans, startv, out, ws);
    crf_combine<<<NB, 64, 0, stream>>>(out, labels, maskp, startv, endv, ws,
                                       out + EMIS_N);
}